// Round 8
// baseline (41.208 us; speedup 1.0000x reference)
//
#include <hip/hip_runtime.h>

namespace {

typedef short  bf16x8 __attribute__((ext_vector_type(8)));
typedef float  f32x4  __attribute__((ext_vector_type(4)));

constexpr int D = 1024;   // in_features
constexpr int O = 1024;   // out_features

// fp32 -> bf16 bits, round-to-nearest-even
__device__ __forceinline__ short f2bf(float f) {
    unsigned u = __builtin_bit_cast(unsigned, f);
    u += 0x7fffu + ((u >> 16) & 1u);
    return (short)(u >> 16);
}

__device__ __forceinline__ bf16x8 cvt8(const float4 a, const float4 b) {
    bf16x8 v;
    v[0] = f2bf(a.x); v[1] = f2bf(a.y); v[2] = f2bf(a.z); v[3] = f2bf(a.w);
    v[4] = f2bf(b.x); v[5] = f2bf(b.y); v[6] = f2bf(b.z); v[7] = f2bf(b.w);
    return v;
}

// Producer/consumer fused LoRA. 256 blocks x 512 threads (8 waves), 64 rows/blk.
// Waves 0-3 (P1): hold dw k-quarter in regs (128 VGPR bf16), compute
//   low partials per 16-row tile (split-K-4), combine in LDS.
// Waves 4-7 (P2): hold up-w o-quarter in regs, compute out(tile i-1) while
//   P1 computes tile i -> HBM reads (hs) overlap HBM writes (out).
// Weights converted f32->bf16 in-reg in the prologue (no prep kernel, no
// weight LDS staging, no bs buffers). LDS = pacc 16KB + lowb 2.3KB.
__global__ void __launch_bounds__(512) lora_pc_k(
        const float* __restrict__ hs,     // [16384][1024] f32
        const float* __restrict__ alpha,  // [4][4]
        const float* __restrict__ dw,     // [64][1024] f32  (k*16+r major)
        const float* __restrict__ uw,     // [4][1024][16] f32
        float* __restrict__ out) {        // [16384][1024] f32
    __shared__ float pacc[4][16][64];               // split-K-4 partials, lane-major
    __shared__ __align__(16) short lowb[16][72];    // bf16 low tile (16 rows x 64 kr)

    const int t    = threadIdx.x;
    const int w    = t >> 6;
    const int lane = t & 63;
    const int fr   = lane & 15;
    const int kgi  = lane >> 4;         // 0..3
    const int kg   = kgi * 8;
    const bool p1w = (w < 4);
    const int wq   = w & 3;             // quarter index within role group
    const int rowblk = blockIdx.x * 64;
    const int b      = rowblk >> 12;    // batch (64-row blocks never straddle)

    // ---------------- prologue: weights -> registers (bf16) ----------------
    bf16x8 regw[32];
    if (p1w) {
        // regw[nt*8+ks] = bf16(dw[nt*16+fr][wq*256 + ks*32 + kg .. +8])
#pragma unroll
        for (int nt = 0; nt < 4; ++nt)
#pragma unroll
            for (int ks = 0; ks < 8; ++ks) {
                const float* sp = dw + (size_t)(nt * 16 + fr) * D + wq * 256 + ks * 32 + kg;
                regw[nt * 8 + ks] = cvt8(*reinterpret_cast<const float4*>(sp),
                                         *reinterpret_cast<const float4*>(sp + 4));
            }
    } else {
        // regw[nt2*2+h] = bf16(wt2[wq*256 + nt2*16 + fr][h*32 + kg .. +8])
        //   wt2[o][kr] = uw[kr>>4][o][kr&15]; kr0 = h*32+kg -> 8 consecutive r
#pragma unroll
        for (int nt2 = 0; nt2 < 16; ++nt2)
#pragma unroll
            for (int h = 0; h < 2; ++h) {
                const int kr0 = h * 32 + kg;
                const int k   = kr0 >> 4;
                const int r0  = kr0 & 15;
                const float* sp = uw + (size_t)k * 16384
                                     + (size_t)(wq * 256 + nt2 * 16 + fr) * 16 + r0;
                regw[nt2 * 2 + h] = cvt8(*reinterpret_cast<const float4*>(sp),
                                         *reinterpret_cast<const float4*>(sp + 4));
            }
    }
    // combine-scale: thread t<256 handles expert nt = t>>6 (index clamped for P2 waves)
    const float sc_comb = alpha[b * 4 + ((t >> 6) & 3)] * 4.0f;   // NETWORK_ALPHA/RANK = 4

    const float* apb = hs + (size_t)(rowblk + fr) * D + wq * 256 + kg;  // P1 base

    // ---------------- pipelined tile loop (4 tiles of 16 rows) ----------------
#pragma unroll 1
    for (int i = 0; i < 5; ++i) {
        if (p1w) {
            if (i < 4) {
                // P1: low partials for tile i over k-quarter wq
                f32x4 acc[4];
#pragma unroll
                for (int nt = 0; nt < 4; ++nt) acc[nt] = (f32x4){0.f, 0.f, 0.f, 0.f};
                const float* ap = apb + (size_t)(i * 16) * D;
#pragma unroll
                for (int ks = 0; ks < 8; ++ks) {
                    const float4 a0 = *reinterpret_cast<const float4*>(ap + ks * 32);
                    const float4 a1 = *reinterpret_cast<const float4*>(ap + ks * 32 + 4);
                    const bf16x8 av = cvt8(a0, a1);
#pragma unroll
                    for (int nt = 0; nt < 4; ++nt)
                        acc[nt] = __builtin_amdgcn_mfma_f32_16x16x32_bf16(
                            av, regw[nt * 8 + ks], acc[nt], 0, 0, 0);
                }
                // pacc[wq][e][lane], e = nt*4+j  (lane-major: conflict-free)
#pragma unroll
                for (int nt = 0; nt < 4; ++nt)
#pragma unroll
                    for (int j = 0; j < 4; ++j)
                        pacc[wq][nt * 4 + j][lane] = acc[nt][j];
            }
        } else {
            if (i > 0) {
                // P2: out tile i-1, o-quarter wq (reads lowb written last window)
                const bf16x8 pa0 = *reinterpret_cast<const bf16x8*>(&lowb[fr][kg]);
                const bf16x8 pa1 = *reinterpret_cast<const bf16x8*>(&lowb[fr][32 + kg]);
                float* op = out + (size_t)(rowblk + (i - 1) * 16 + kgi * 4) * O + wq * 256;
#pragma unroll
                for (int nt2 = 0; nt2 < 16; ++nt2) {
                    f32x4 c2 = (f32x4){0.f, 0.f, 0.f, 0.f};
                    c2 = __builtin_amdgcn_mfma_f32_16x16x32_bf16(pa0, regw[nt2 * 2],     c2, 0, 0, 0);
                    c2 = __builtin_amdgcn_mfma_f32_16x16x32_bf16(pa1, regw[nt2 * 2 + 1], c2, 0, 0, 0);
#pragma unroll
                    for (int j = 0; j < 4; ++j)
                        op[(size_t)j * O + nt2 * 16 + fr] = c2[j];
                }
            }
        }
        __syncthreads();   // pacc(i) visible; P2's lowb reads done

        // combine tile i: sum 4 k-quarters, scale by alpha*4, cvt -> lowb
        // thread t<256: expert/e-group nt = t>>6 = wq, lane index = lane
        if (p1w && i < 4) {
#pragma unroll
            for (int j = 0; j < 4; ++j) {
                const int e = wq * 4 + j;
                const float s = pacc[0][e][lane] + pacc[1][e][lane]
                              + pacc[2][e][lane] + pacc[3][e][lane];
                // (e,lane) encodes low[row=(lane>>4)*4+j'... ] via frag map:
                // value at acc[nt=wq][j] of lane -> low[row=(lane>>4)*4+j][kr=wq*16+(lane&15)]
                lowb[(lane >> 4) * 4 + j][wq * 16 + (lane & 15)] = f2bf(s * sc_comb);
            }
        }
        __syncthreads();   // lowb(i) ready for P2 next window; pacc free for i+1
    }
}

} // namespace

extern "C" void kernel_launch(void* const* d_in, const int* in_sizes, int n_in,
                              void* d_out, int out_size, void* d_ws, size_t ws_size,
                              hipStream_t stream) {
    const float* hs    = (const float*)d_in[0];  // [4,4096,1024]
    const float* alpha = (const float*)d_in[1];  // [4,4]
    const float* dw    = (const float*)d_in[2];  // [4,16,1024]
    const float* uw    = (const float*)d_in[3];  // [4,1024,16]
    float* outp = (float*)d_out;

    hipLaunchKernelGGL(lora_pc_k, dim3(256), dim3(512), 0, stream,
                       hs, alpha, dw, uw, outp);
}

// Round 9
// 32.736 us; speedup vs baseline: 1.2588x; 1.2588x over previous
//
#include <hip/hip_runtime.h>

namespace {

typedef short  bf16x8 __attribute__((ext_vector_type(8)));
typedef float  f32x4  __attribute__((ext_vector_type(4)));

constexpr int D = 1024;   // in_features
constexpr int O = 1024;   // out_features

// fp32 -> bf16 bits, round-to-nearest-even
__device__ __forceinline__ short f2bf(float f) {
    unsigned u = __builtin_bit_cast(unsigned, f);
    u += 0x7fffu + ((u >> 16) & 1u);
    return (short)(u >> 16);
}

__device__ __forceinline__ bf16x8 cvt8(const float4 a, const float4 b) {
    bf16x8 v;
    v[0] = f2bf(a.x); v[1] = f2bf(a.y); v[2] = f2bf(a.z); v[3] = f2bf(a.w);
    v[4] = f2bf(b.x); v[5] = f2bf(b.y); v[6] = f2bf(b.z); v[7] = f2bf(b.w);
    return v;
}

__device__ __forceinline__ float4 ld4(const float* p) {
    return *reinterpret_cast<const float4*>(p);
}

struct StageRegs { float4 a[4]; float4 b[4]; };

// dw staging (512 threads cooperate, coalesced dwordx4; full unroll = static idx)
__device__ __forceinline__ void issue_dw(const float* __restrict__ dw, int c, int t,
                                         StageRegs& r) {
#pragma unroll
    for (int i = 0; i < 4; ++i) {
        const int e = i * 512 + t, kr = e >> 5, cc = e & 31;
        const float* sp = dw + (size_t)kr * D + c * 256 + cc * 8;
        r.a[i] = ld4(sp);
        r.b[i] = ld4(sp + 4);
    }
}
__device__ __forceinline__ void write_p1(short* buf, int t, const StageRegs& r) {
#pragma unroll
    for (int i = 0; i < 4; ++i) {
        const int e = i * 512 + t, kr = e >> 5, cc = e & 31;
        *reinterpret_cast<bf16x8*>(&buf[kr * 264 + cc * 8]) = cvt8(r.a[i], r.b[i]);
    }
}

// Fused LoRA. 256 blocks x 512 threads (8 waves, 1 block/CU, 64 rows/block).
// Phase 1: dw LDS double-buffer (R7) + hs chunk prefetched to regs one chunk
//   ahead -> compute never waits on HBM. Wave w: rt=w>>1 (16-row tile),
//   kh=w&1 (K-half); split-K-2 combine via pacc.
// Phase 2: wt2 o-eighth per wave held in REGISTERS (loaded in prologue) ->
//   pure MFMA+store, no staging, no barriers. 6 barriers total.
__global__ void __launch_bounds__(512) lora_mfma_k(
        const float* __restrict__ hs,     // [16384][1024] f32
        const float* __restrict__ alpha,  // [4][4]
        const float* __restrict__ dw,     // [64][1024] f32  (k*16+r major)
        const float* __restrict__ uw,     // [4][1024][16] f32
        float* __restrict__ out) {        // [16384][1024] f32
    __shared__ __align__(16) short bs[2][64 * 264];  // 67.6 KB dw chunks
    __shared__ __align__(16) short lowb[4][16][72];  // 9.2 KB
    __shared__ float pacc[4][16][64];                // 16 KB

    const int t    = threadIdx.x;
    const int w    = t >> 6;
    const int lane = t & 63;
    const int fr   = lane & 15;
    const int kgi  = lane >> 4;         // 0..3
    const int kg   = kgi * 8;
    const int rt   = w >> 1;            // row-tile 0..3
    const int kh   = w & 1;             // K-half
    const int rowblk = blockIdx.x * 64;
    const int b      = rowblk >> 12;    // batch (blocks never straddle)
    const int myrow  = rowblk + rt * 16 + fr;
    const float* apb = hs + (size_t)myrow * D + kh * 128 + kg;

    // ---------------- prologue ----------------
    StageRegs rg;
    issue_dw(dw, 0, t, rg);                        // dw chunk 0 (oldest in queue)

    float4 pf[8];                                  // hs chunk-0 prefetch
#pragma unroll
    for (int ks = 0; ks < 4; ++ks) {
        pf[2 * ks]     = ld4(apb + ks * 32);
        pf[2 * ks + 1] = ld4(apb + ks * 32 + 4);
    }

    // wt2 o-eighth -> registers: wreg[nt2l*2+h] = bf16(wt2[w*128+nt2l*16+fr][h*32+kg ..+8])
    bf16x8 wreg[16];
#pragma unroll
    for (int nt2l = 0; nt2l < 8; ++nt2l)
#pragma unroll
        for (int h = 0; h < 2; ++h) {
            const int kr0 = h * 32 + kg;
            const int k   = kr0 >> 4;
            const int r0  = kr0 & 15;
            const float* sp = uw + (size_t)k * 16384
                                 + (size_t)(w * 128 + nt2l * 16 + fr) * 16 + r0;
            wreg[nt2l * 2 + h] = cvt8(ld4(sp), ld4(sp + 4));
        }

    write_p1(&bs[0][0], t, rg);                    // waits only on dw loads
    __syncthreads();

    // ---------------- phase 1: low = hs @ dw^T ----------------
    f32x4 acc[4];
#pragma unroll
    for (int nt = 0; nt < 4; ++nt) acc[nt] = (f32x4){0.f, 0.f, 0.f, 0.f};

#pragma unroll
    for (int c = 0; c < 4; ++c) {
        // convert this chunk's prefetched hs to bf16 (loads completed a chunk ago)
        bf16x8 av[4];
#pragma unroll
        for (int ks = 0; ks < 4; ++ks) av[ks] = cvt8(pf[2 * ks], pf[2 * ks + 1]);

        if (c < 3) {
            // prefetch hs chunk c+1 into freed pf regs
            const float* ap = apb + (c + 1) * 256;
#pragma unroll
            for (int ks = 0; ks < 4; ++ks) {
                pf[2 * ks]     = ld4(ap + ks * 32);
                pf[2 * ks + 1] = ld4(ap + ks * 32 + 4);
            }
            issue_dw(dw, c + 1, t, rg);            // dw chunk c+1 -> regs
        }

        // compute chunk c: LDS B-frags + MFMA
#pragma unroll
        for (int ks = 0; ks < 4; ++ks)
#pragma unroll
            for (int nt = 0; nt < 4; ++nt) {
                const bf16x8 bv = *reinterpret_cast<const bf16x8*>(
                    &bs[c & 1][(nt * 16 + fr) * 264 + kh * 128 + ks * 32 + kg]);
                acc[nt] = __builtin_amdgcn_mfma_f32_16x16x32_bf16(av[ks], bv, acc[nt], 0, 0, 0);
            }

        if (c < 3) {
            write_p1(&bs[(c + 1) & 1][0], t, rg);  // waits on dw c+1 loads (overlapped)
            __syncthreads();
        }
    }

    // ---------------- combine split-K, scale, cvt -> lowb ----------------
    if (kh) {
#pragma unroll
        for (int nt = 0; nt < 4; ++nt)
#pragma unroll
            for (int j = 0; j < 4; ++j)
                pacc[rt][nt * 4 + j][lane] = acc[nt][j];
    }
    __syncthreads();
    if (!kh) {
#pragma unroll
        for (int nt = 0; nt < 4; ++nt) {
            const float sc = alpha[b * 4 + nt] * 4.0f;   // NETWORK_ALPHA/RANK = 4
#pragma unroll
            for (int j = 0; j < 4; ++j) {
                const float v = (acc[nt][j] + pacc[rt][nt * 4 + j][lane]) * sc;
                lowb[rt][kgi * 4 + j][nt * 16 + fr] = f2bf(v);
            }
        }
    }
    __syncthreads();

    // ---------------- phase 2: out = low @ wt2^T (registers, no barriers) ----------------
#pragma unroll
    for (int rt2 = 0; rt2 < 4; ++rt2) {
        const bf16x8 pa0 = *reinterpret_cast<const bf16x8*>(&lowb[rt2][fr][kg]);
        const bf16x8 pa1 = *reinterpret_cast<const bf16x8*>(&lowb[rt2][fr][32 + kg]);
        float* op = out + (size_t)(rowblk + rt2 * 16 + kgi * 4) * O + w * 128;
#pragma unroll
        for (int nt2l = 0; nt2l < 8; ++nt2l) {
            f32x4 c2 = (f32x4){0.f, 0.f, 0.f, 0.f};
            c2 = __builtin_amdgcn_mfma_f32_16x16x32_bf16(pa0, wreg[nt2l * 2],     c2, 0, 0, 0);
            c2 = __builtin_amdgcn_mfma_f32_16x16x32_bf16(pa1, wreg[nt2l * 2 + 1], c2, 0, 0, 0);
#pragma unroll
            for (int j = 0; j < 4; ++j)
                op[(size_t)j * O + nt2l * 16 + fr] = c2[j];
        }
    }
}

} // namespace

extern "C" void kernel_launch(void* const* d_in, const int* in_sizes, int n_in,
                              void* d_out, int out_size, void* d_ws, size_t ws_size,
                              hipStream_t stream) {
    const float* hs    = (const float*)d_in[0];  // [4,4096,1024]
    const float* alpha = (const float*)d_in[1];  // [4,4]
    const float* dw    = (const float*)d_in[2];  // [4,16,1024]
    const float* uw    = (const float*)d_in[3];  // [4,1024,16]
    float* outp = (float*)d_out;

    hipLaunchKernelGGL(lora_mfma_k, dim3(256), dim3(512), 0, stream,
                       hs, alpha, dw, uw, outp);
}